// Round 5
// baseline (341.011 us; speedup 1.0000x reference)
//
#include <hip/hip_runtime.h>
#include <math.h>

#define NT 256
#define NTG 1024
constexpr int B_   = 8192;
constexpr int N_   = 100;
constexpr int E_   = 1600;
constexpr int EMB  = 5;
constexpr int XDIM = 500;    // N_*EMB
constexpr int DDIM = 2600;   // 50*52
constexpr int XWP  = 512;    // padded x-region width ([500,512) = 0)
constexpr int DOFF = 512;    // d-region start in k' space
constexpr int KPAD = 3136;   // k' = 98 kchunks of 32
constexpr int NKC  = 98;     // kchunks per row (F1c)
constexpr int XKC  = 16;     // kchunks stored in awf (x-region only)
constexpr int H1 = 128, H2 = 128, H3 = 64, HO = 2;
constexpr int EST = 136;

typedef short short8 __attribute__((ext_vector_type(8)));
typedef float f32x4  __attribute__((ext_vector_type(4)));

__device__ __forceinline__ float leaky(float v) { return v > 0.f ? v : 0.01f * v; }
__device__ __forceinline__ float sigm(float v)  { return 1.f / (1.f + __expf(-v)); }
__device__ __forceinline__ unsigned short f2bf(float f) {   // RNE fp32->bf16
  unsigned int x = __float_as_uint(f);
  return (unsigned short)((x + 0x7fffu + ((x >> 16) & 1u)) >> 16);
}

// Fragment layout (mfma_f32_16x16x32_bf16 operands):
//   frag(R, kc)[lane][e] = M[R*16 + (lane&15)][kc*32 + (lane>>4)*8 + e]
//   awf linear: awf[((R*XKC + kc)*64 + lane)*8 + e]  (x-region, kc<16)
//   F1c linear: F1c[((cb*NKC + kc)*64 + lane)*8 + e]

// ---------------- Kernel A: setup (csr | weight prep) -------------------------
__global__ __launch_bounds__(NT) void setup_kernel(
    const int* __restrict__ src, const int* __restrict__ dst,
    int* __restrict__ off_g, int* __restrict__ lst_g,
    const float* __restrict__ F1, const float* __restrict__ F2, const float* __restrict__ F3,
    unsigned short* __restrict__ F1c, unsigned short* __restrict__ F2T, unsigned short* __restrict__ F3T)
{
  const int blk = blockIdx.x;
  const int t   = threadIdx.x;

  if (blk == 0) {
    // ---- CSR (dst-sorted) ----
    __shared__ int cnt[N_ + 1];
    __shared__ int cur[N_];
    if (t <= N_) cnt[t] = 0;
    __syncthreads();
    for (int e = t; e < E_; e += NT) atomicAdd(&cnt[dst[e] + 1], 1);
    __syncthreads();
    if (t == 0) {
      int s = 0;
      for (int n = 0; n <= N_; ++n) { s += cnt[n]; cnt[n] = s; }
    }
    __syncthreads();
    if (t < N_) cur[t] = cnt[t];
    if (t <= N_) off_g[t] = cnt[t];
    __syncthreads();
    for (int e = t; e < E_; e += NT) {
      int d = dst[e];
      int p = atomicAdd(&cur[d], 1);
      lst_g[p] = src[e];
    }
  } else {
    const int b = blk - 1;
    if (b < 128) {
      // F1 -> fragment-ordered F1c (col b: colblk b>>4, frag row b&15)
      for (int k = t; k < KPAD; k += NT) {
        float v = 0.f;
        if (k < XDIM)                          v = F1[(size_t)k * H1 + b];
        else if (k >= DOFF && k < DOFF + DDIM) v = F1[(size_t)(k - DOFF + XDIM) * H1 + b];
        int kc = k >> 5, q = (k >> 3) & 3, e = k & 7;
        int lane = (b & 15) + q * 16;
        F1c[((size_t)(b >> 4) * NKC + kc) * 512 + lane * 8 + e] = f2bf(v);
      }
    } else if (b < 256) {
      int n = b - 128;
      if (t < 128) F2T[n * 128 + t] = f2bf(F2[(size_t)t * H2 + n]);
    } else {
      int n = b - 256;
      if (n < 64 && t < 128) F3T[n * 128 + t] = f2bf(F3[(size_t)t * H3 + n]);
    }
  }
}

// ---------------- Kernel C: gated RGCN, batch-along-lanes ---------------------
constexpr int BT2 = 32;

__device__ __forceinline__ void rgcn_layer(
    const float* __restrict__ RB, float* __restrict__ WB,
    const float* __restrict__ wts, const int* __restrict__ soff,
    const int* __restrict__ sl160, int t, int wof)
{
  if (t < N_ * (BT2 / 4)) {                  // 800 items: (node, batch-quad)
    const int n  = t >> 3;
    const int b4 = (t & 7) * 4;
    f32x4 a[5];
#pragma unroll
    for (int j = 0; j < 5; ++j) a[j] = (f32x4){0.f, 0.f, 0.f, 0.f};
    const int qe = soff[n + 1];
    for (int q = soff[n]; q < qe; ++q) {
      const float* base = RB + sl160[q] + b4;
#pragma unroll
      for (int j = 0; j < 5; ++j) a[j] += *(const f32x4*)(base + j * 32);
    }
    f32x4 h2[5];
#pragma unroll
    for (int j = 0; j < 5; ++j) {
      float bb = wts[wof + 25 + j];
      f32x4 v = (f32x4){bb, bb, bb, bb};
#pragma unroll
      for (int k = 0; k < 5; ++k) v += a[k] * wts[wof + k * 5 + j];
      h2[j] = v;
    }
#pragma unroll
    for (int j = 0; j < 5; ++j) {
      float gb = wts[wof + 55 + j];
      f32x4 g = (f32x4){gb, gb, gb, gb};
#pragma unroll
      for (int k = 0; k < 5; ++k) g += h2[k] * wts[wof + 30 + k * 5 + j];
      f32x4 o;
#pragma unroll
      for (int c = 0; c < 4; ++c) o[c] = leaky(sigm(g[c]) * h2[j][c]);
      *(f32x4*)(WB + n * 160 + j * 32 + b4) = o;
    }
  }
}

__global__ __launch_bounds__(NTG) void gnn_kernel(
    const float* __restrict__ data,
    const int* __restrict__ off_g, const int* __restrict__ lst_g,
    const float* __restrict__ W0, const float* __restrict__ b0, const float* __restrict__ G0, const float* __restrict__ gb0,
    const float* __restrict__ W1, const float* __restrict__ b1, const float* __restrict__ G1, const float* __restrict__ gb1,
    const float* __restrict__ W2, const float* __restrict__ b2, const float* __restrict__ G2, const float* __restrict__ gb2,
    unsigned short* __restrict__ awf)
{
  __shared__ __attribute__((aligned(16))) float bufA[BT2 * 513];  // 65.7 KB
  __shared__ __attribute__((aligned(16))) float bufB[XDIM * BT2]; // 64 KB
  __shared__ int   soff[N_ + 1];
  __shared__ int   sl160[E_];
  __shared__ float wts[160];
  const int t   = threadIdx.x;
  const int b0_ = blockIdx.x * BT2;

  for (int i = t; i < E_; i += NTG) sl160[i] = lst_g[i] * 160;
  if (t <= N_) soff[t] = off_g[t];
  if (t < 5)  { wts[t] = W0[t]; wts[5 + t] = b0[t]; wts[35 + t] = gb0[t]; }
  if (t < 25) { wts[10 + t] = G0[t];
                wts[40 + t] = W1[t]; wts[70 + t]  = G1[t];
                wts[100 + t] = W2[t]; wts[130 + t] = G2[t]; }
  if (t < 5)  { wts[65 + t] = b1[t]; wts[95 + t]  = gb1[t];
                wts[125 + t] = b2[t]; wts[155 + t] = gb2[t]; }
  // coalesced input: 3200 contiguous floats, scatter into j=0 state slots
  for (int i = t; i < N_ * BT2; i += NTG) {
    int b = i / N_, n = i - b * N_;
    bufA[n * 160 + b] = data[(size_t)b0_ * N_ + i];
  }
  __syncthreads();

  // ---- Layer 0 (scalar input), vectorized over 4 batches/lane ----
  if (t < N_ * (BT2 / 4)) {
    const int n  = t >> 3;
    const int b4 = (t & 7) * 4;
    f32x4 a = (f32x4){0.f, 0.f, 0.f, 0.f};
    const int qe = soff[n + 1];
    for (int q = soff[n]; q < qe; ++q) a += *(const f32x4*)(bufA + sl160[q] + b4);
    f32x4 h2[5];
#pragma unroll
    for (int j = 0; j < 5; ++j) {
      float bb = wts[5 + j];
      h2[j] = a * wts[j] + (f32x4){bb, bb, bb, bb};
    }
#pragma unroll
    for (int j = 0; j < 5; ++j) {
      float gb = wts[35 + j];
      f32x4 g = (f32x4){gb, gb, gb, gb};
#pragma unroll
      for (int k = 0; k < 5; ++k) g += h2[k] * wts[10 + k * 5 + j];
      f32x4 o;
#pragma unroll
      for (int c = 0; c < 4; ++c) o[c] = leaky(sigm(g[c]) * h2[j][c]);
      *(f32x4*)(bufB + n * 160 + j * 32 + b4) = o;
    }
  }
  __syncthreads();

  rgcn_layer(bufB, bufA, wts, soff, sl160, t, 40);    // layer 1: B -> A
  __syncthreads();
  rgcn_layer(bufA, bufB, wts, soff, sl160, t, 100);   // layer 2: A -> B
  __syncthreads();

  // transpose bufB[jn][b] -> bufA[b*513 + r] (write banks (b+r)%32: conflict-free)
  for (int i = t; i < BT2 * XWP; i += NTG) {
    int b = i & 31, r = i >> 5;
    bufA[b * 513 + r] = (r < XDIM) ? bufB[r * 32 + b] : 0.f;
  }
  __syncthreads();

  // fragment-ordered store: x-region kchunks 0..15 of rowblks R0, R0+1
  {
    const int R0 = blockIdx.x * 2;
    for (int i = t; i < 32 * 64; i += NTG) {   // 32 frags x 64 lanes
      int f = i >> 6, lane = i & 63;
      int h = f >> 4, kc = f & 15;
      int b = h * 16 + (lane & 15);
      int k0 = kc * 32 + (lane >> 4) * 8;
      const float* sp = bufA + b * 513 + k0;
      uint4 p;
      p.x = (unsigned)f2bf(sp[0]) | ((unsigned)f2bf(sp[1]) << 16);
      p.y = (unsigned)f2bf(sp[2]) | ((unsigned)f2bf(sp[3]) << 16);
      p.z = (unsigned)f2bf(sp[4]) | ((unsigned)f2bf(sp[5]) << 16);
      p.w = (unsigned)f2bf(sp[6]) | ((unsigned)f2bf(sp[7]) << 16);
      ((uint4*)awf)[((size_t)(R0 + h) * XKC + kc) * 64 + lane] = p;
    }
  }
}

// ---------------- Kernel D: fused GEMM1(+d staging) + MLP tail ----------------
// 16 rows/block, 512 thr (8 waves: wave w = colblk w of H1). Full K, no split.
// x from awf fragments (global); d staged fp32->bf16 in LDS tiles of 512 cols.
__global__ __launch_bounds__(512, 4) void mlp_fused(
    const unsigned short* __restrict__ awf,
    const unsigned short* __restrict__ F1c,
    const float* __restrict__ dmat,
    const float* __restrict__ fb1,
    const unsigned short* __restrict__ F2T, const float* __restrict__ fb2,
    const unsigned short* __restrict__ F3T, const float* __restrict__ fb3,
    const float* __restrict__ F4, const float* __restrict__ fb4,
    float* __restrict__ out)
{
  __shared__ __attribute__((aligned(16))) unsigned short tile[16][520];  // 16.6 KB
  __shared__ __attribute__((aligned(16))) unsigned short sH[16 * EST];
  __shared__ float sh3[16 * 68];

  const int t    = threadIdx.x;
  const int rb   = blockIdx.x;          // 0..511
  const int row0 = rb * 16;
  const int lane = t & 63;
  const int w    = t >> 6;              // 0..7 colblk
  const int r    = lane & 15;
  const int q    = lane >> 4;
  const int q8   = q * 8;

  const unsigned short* ap = awf + (size_t)rb * XKC * 512 + lane * 8;
  const unsigned short* bp = F1c + (size_t)w * NKC * 512 + lane * 8;
  const float* dbase = dmat + (size_t)row0 * DDIM;

  f32x4 acc = {0.f, 0.f, 0.f, 0.f};
  short8 Ar[2], Br[2];
  float4 sv[4];

  Ar[0] = *(const short8*)(ap);
  Ar[1] = *(const short8*)(ap + 512);
  Br[0] = *(const short8*)(bp);
  Br[1] = *(const short8*)(bp + 512);
  // issue stage loads for d-tile 0 (cols 0..511)
#pragma unroll
  for (int i = 0; i < 4; ++i) {
    int e = i * 512 + t, rr = e >> 7, cc = e & 127;
    sv[i] = *(const float4*)(dbase + (size_t)rr * DDIM + cc * 4);
  }
  // ---- x-phase: kc 0..15 (global fragments), B-ring rolls over all kc ----
  for (int kc = 0; kc < 16; ++kc) {
    int cur = kc & 1;
    short8 a = Ar[cur], b = Br[cur];
    if (kc < 14) Ar[cur] = *(const short8*)(ap + (kc + 2) * 512);
    Br[cur] = *(const short8*)(bp + (kc + 2) * 512);
    acc = __builtin_amdgcn_mfma_f32_16x16x32_bf16(a, b, acc, 0, 0, 0);
  }
  // write d-tile 0 (truncate fp32->bf16)
#pragma unroll
  for (int i = 0; i < 4; ++i) {
    int e = i * 512 + t, rr = e >> 7, cc = e & 127;
    uint2 p;
    p.x = (__float_as_uint(sv[i].y) & 0xffff0000u) | (__float_as_uint(sv[i].x) >> 16);
    p.y = (__float_as_uint(sv[i].w) & 0xffff0000u) | (__float_as_uint(sv[i].z) >> 16);
    *(uint2*)&tile[rr][cc * 4] = p;
  }
  __syncthreads();

  // ---- d-phase: 5 full tiles (16 kc) + 1 partial tile (2 kc) ----
  const unsigned short* tb = &tile[r][q8];
  for (int ct = 0; ct < 6; ++ct) {
    const int nk   = (ct < 5) ? 16 : 2;
    const int kcg0 = 16 + ct * 16;
    // issue next-tile stage loads (regs only; no LDS hazard)
    if (ct < 4) {
#pragma unroll
      for (int i = 0; i < 4; ++i) {
        int e = i * 512 + t, rr = e >> 7, cc = e & 127;
        sv[i] = *(const float4*)(dbase + (size_t)rr * DDIM + (ct + 1) * 512 + cc * 4);
      }
    } else if (ct == 4) {
      if (t < 160) {                     // 16 rows x 10 float4 (cols 2560..2599)
        int rr = t / 10, cc = t % 10;
        sv[0] = *(const float4*)(dbase + (size_t)rr * DDIM + 2560 + cc * 4);
      }
    }
    // consume nk kchunks from tile
    short8 Dr[2];
    Dr[0] = *(const short8*)(tb);
    Dr[1] = *(const short8*)(tb + 32);
    for (int kcL = 0; kcL < nk; ++kcL) {
      int kc  = kcg0 + kcL;
      int cur = kcL & 1;
      short8 a = Dr[cur], b = Br[kc & 1];
      if (kcL + 2 < nk)  Dr[cur]    = *(const short8*)(tb + (kcL + 2) * 32);
      if (kc + 2 < NKC)  Br[kc & 1] = *(const short8*)(bp + (kc + 2) * 512);
      acc = __builtin_amdgcn_mfma_f32_16x16x32_bf16(a, b, acc, 0, 0, 0);
    }
    if (ct == 5) break;
    __syncthreads();
    // write next tile
    if (ct < 4) {
#pragma unroll
      for (int i = 0; i < 4; ++i) {
        int e = i * 512 + t, rr = e >> 7, cc = e & 127;
        uint2 p;
        p.x = (__float_as_uint(sv[i].y) & 0xffff0000u) | (__float_as_uint(sv[i].x) >> 16);
        p.y = (__float_as_uint(sv[i].w) & 0xffff0000u) | (__float_as_uint(sv[i].z) >> 16);
        *(uint2*)&tile[rr][cc * 4] = p;
      }
    } else {                             // partial tile: 40 data cols + zero pad
      if (t < 160) {
        int rr = t / 10, cc = t % 10;
        uint2 p;
        p.x = (__float_as_uint(sv[0].y) & 0xffff0000u) | (__float_as_uint(sv[0].x) >> 16);
        p.y = (__float_as_uint(sv[0].w) & 0xffff0000u) | (__float_as_uint(sv[0].z) >> 16);
        *(uint2*)&tile[rr][cc * 4] = p;
      } else if (t < 256) {              // zero cols 40..63 (k' 3112..3136)
        int idx = t - 160, r2 = idx / 6, c2 = 40 + (idx % 6) * 4;
        *(uint2*)&tile[r2][c2] = make_uint2(0u, 0u);
      }
    }
    __syncthreads();
  }

  // ---- h1 = leaky(acc + fb1) -> sH ----
  {
    float b1v = fb1[w * 16 + r];
#pragma unroll
    for (int reg = 0; reg < 4; ++reg) {
      int m = q * 4 + reg;
      sH[m * EST + w * 16 + r] = f2bf(leaky(acc[reg] + b1v));
    }
  }
  __syncthreads();

  // ---- h2 = leaky(h1 @ F2 + fb2): 8 waves x colblk ----
  f32x4 a2 = {0.f, 0.f, 0.f, 0.f};
  {
    const unsigned short* g2 = F2T + (size_t)(w * 16 + r) * H2 + q8;
#pragma unroll
    for (int s = 0; s < 4; ++s) {
      short8 bf = *(const short8*)(g2 + s * 32);
      short8 af = *(const short8*)(sH + r * EST + s * 32 + q8);
      a2 = __builtin_amdgcn_mfma_f32_16x16x32_bf16(af, bf, a2, 0, 0, 0);
    }
  }
  __syncthreads();
  {
    float b2v = fb2[w * 16 + r];
#pragma unroll
    for (int reg = 0; reg < 4; ++reg) {
      int m = q * 4 + reg;
      sH[m * EST + w * 16 + r] = f2bf(leaky(a2[reg] + b2v));
    }
  }
  __syncthreads();

  // ---- h3 = leaky(h2 @ F3 + fb3): waves 0..3 ----
  if (w < 4) {
    f32x4 a3 = {0.f, 0.f, 0.f, 0.f};
    const unsigned short* g3 = F3T + (size_t)(w * 16 + r) * H2 + q8;
#pragma unroll
    for (int s = 0; s < 4; ++s) {
      short8 bf = *(const short8*)(g3 + s * 32);
      short8 af = *(const short8*)(sH + r * EST + s * 32 + q8);
      a3 = __builtin_amdgcn_mfma_f32_16x16x32_bf16(af, bf, a3, 0, 0, 0);
    }
    float b3v = fb3[w * 16 + r];
#pragma unroll
    for (int reg = 0; reg < 4; ++reg)
      sh3[(q * 4 + reg) * 68 + w * 16 + r] = leaky(a3[reg] + b3v);
  }
  __syncthreads();

  // ---- out = sigmoid(h3 @ F4 + fb4) ----
  if (t < 16 * HO) {
    int m = t >> 1, j = t & 1;
    float a = fb4[j];
#pragma unroll 8
    for (int k = 0; k < H3; ++k) a += sh3[m * 68 + k] * F4[k * HO + j];
    out[(size_t)(row0 + m) * HO + j] = sigm(a);
  }
}

// ---------------- launch ------------------------------------------------------
extern "C" void kernel_launch(void* const* d_in, const int* in_sizes, int n_in,
                              void* d_out, int out_size, void* d_ws, size_t ws_size,
                              hipStream_t stream) {
  const float* data = (const float*)d_in[0];
  const float* dmat = (const float*)d_in[1];
  const int*   src  = (const int*)d_in[2];
  const int*   dst  = (const int*)d_in[3];
  const float* W0 = (const float*)d_in[4];  const float* b0 = (const float*)d_in[5];
  const float* G0 = (const float*)d_in[6];  const float* gb0 = (const float*)d_in[7];
  const float* W1 = (const float*)d_in[8];  const float* b1 = (const float*)d_in[9];
  const float* G1 = (const float*)d_in[10]; const float* gb1 = (const float*)d_in[11];
  const float* W2 = (const float*)d_in[12]; const float* b2 = (const float*)d_in[13];
  const float* G2 = (const float*)d_in[14]; const float* gb2 = (const float*)d_in[15];
  const float* F1 = (const float*)d_in[16]; const float* fb1 = (const float*)d_in[17];
  const float* F2 = (const float*)d_in[18]; const float* fb2 = (const float*)d_in[19];
  const float* F3 = (const float*)d_in[20]; const float* fb3 = (const float*)d_in[21];
  const float* F4 = (const float*)d_in[22]; const float* fb4 = (const float*)d_in[23];
  float* out = (float*)d_out;

  unsigned short* awf = (unsigned short*)d_ws;          // 512*16*512 shorts (8.4 MB)
  unsigned short* F1c = awf + (size_t)(B_ / 16) * XKC * 512;  // 8*98*512
  unsigned short* F2T = F1c + 128 * KPAD;               // 128*128
  unsigned short* F3T = F2T + 128 * 128;                // 64*128
  int* off_g = (int*)(F3T + 64 * 128);                  // 101 (pad 104)
  int* lst_g = off_g + 104;                             // 1600

  setup_kernel<<<321, NT, 0, stream>>>(src, dst, off_g, lst_g,
                                       F1, F2, F3, F1c, F2T, F3T);
  gnn_kernel<<<B_ / BT2, NTG, 0, stream>>>(data, off_g, lst_g,
                                           W0, b0, G0, gb0,
                                           W1, b1, G1, gb1,
                                           W2, b2, G2, gb2, awf);
  mlp_fused<<<B_ / 16, 512, 0, stream>>>(awf, F1c, dmat, fb1, F2T, fb2,
                                         F3T, fb3, F4, fb4, out);
}